// Round 11
// baseline (36.499 us; speedup 1.0000x reference)
//
#include <hip/hip_runtime.h>
#include <hip/hip_fp16.h>

#define D_FEAT  128
#define PAD     16      // floats per seg_sum slot = one 64B line per node

// Dispatch 1: convert feats f32 -> f16 and zero the padded seg_sum slots.
// fp16 table = 2.56 MB -> L2-resident per XCD (confirmed ~-2us on eval, R10).
__global__ void convert_zero_kernel(const float* __restrict__ feats,
                                    __half* __restrict__ feats16,
                                    float* __restrict__ seg_sum,
                                    int total8, int N) {
    int i = blockIdx.x * blockDim.x + threadIdx.x;
    if (i < N) seg_sum[(size_t)i * PAD] = 0.0f;
    if (i >= total8) return;
    float4 v0 = ((const float4*)feats)[2 * i];
    float4 v1 = ((const float4*)feats)[2 * i + 1];
    __half2 h[4];
    h[0] = __floats2half2_rn(v0.x, v0.y);
    h[1] = __floats2half2_rn(v0.z, v0.w);
    h[2] = __floats2half2_rn(v1.x, v1.y);
    h[3] = __floats2half2_rn(v1.z, v1.w);
    ((uint4*)feats16)[i] = *reinterpret_cast<uint4*>(h);
}

__device__ inline float l1_u32(unsigned ua, unsigned ub) {
    __half2 ha = *reinterpret_cast<__half2*>(&ua);
    __half2 hb = *reinterpret_cast<__half2*>(&ub);
    float2 fa = __half22float2(ha);
    float2 fb = __half22float2(hb);
    return fabsf(fa.x - fb.x) + fabsf(fa.y - fb.y);
}
__device__ inline float l1_u4(uint4 a, uint4 b) {
    return l1_u32(a.x, b.x) + l1_u32(a.y, b.y)
         + l1_u32(a.z, b.z) + l1_u32(a.w, b.w);
}

// Dispatch 2: 8 lanes per group, 4 EDGES per group (MLP test).
// All 16 uint4 gathers (4 edges x 2 rows x 2 chunks) are issued before any
// dependent math -> 256 B/lane outstanding, hides L2-hit latency.
// Edge indices arrive as one int4 per array; out written as one float4.
// seg_sum padded one 64B line/node (R8, -6.4us). seg_max pass dropped:
// softmax shift invariance, e = exp(-0.01*L1) in (0,1] -> exp(e) <= 2.72.
__global__ void edge_eval_kernel(const __half* __restrict__ feats16,
                                 const int* __restrict__ src,
                                 const int* __restrict__ dst,
                                 float* __restrict__ seg_sum,
                                 float* __restrict__ out,
                                 int E) {
    int gtid = blockIdx.x * blockDim.x + threadIdx.x;
    int g    = gtid >> 3;         // 8-lane group id
    int sl   = threadIdx.x & 7;
    int base = g << 2;            // 4 edges per group
    if (base >= E) return;

    if (base + 4 <= E) {
        int4 s4 = ((const int4*)src)[g];
        int4 d4 = ((const int4*)dst)[g];

        const uint4* fa0 = (const uint4*)(feats16 + (size_t)s4.x * D_FEAT);
        const uint4* fb0 = (const uint4*)(feats16 + (size_t)d4.x * D_FEAT);
        const uint4* fa1 = (const uint4*)(feats16 + (size_t)s4.y * D_FEAT);
        const uint4* fb1 = (const uint4*)(feats16 + (size_t)d4.y * D_FEAT);
        const uint4* fa2 = (const uint4*)(feats16 + (size_t)s4.z * D_FEAT);
        const uint4* fb2 = (const uint4*)(feats16 + (size_t)d4.z * D_FEAT);
        const uint4* fa3 = (const uint4*)(feats16 + (size_t)s4.w * D_FEAT);
        const uint4* fb3 = (const uint4*)(feats16 + (size_t)d4.w * D_FEAT);

        // issue all 16 loads before any dependent use
        uint4 a00 = fa0[sl], a01 = fa0[sl + 8];
        uint4 b00 = fb0[sl], b01 = fb0[sl + 8];
        uint4 a10 = fa1[sl], a11 = fa1[sl + 8];
        uint4 b10 = fb1[sl], b11 = fb1[sl + 8];
        uint4 a20 = fa2[sl], a21 = fa2[sl + 8];
        uint4 b20 = fb2[sl], b21 = fb2[sl + 8];
        uint4 a30 = fa3[sl], a31 = fa3[sl + 8];
        uint4 b30 = fb3[sl], b31 = fb3[sl + 8];

        float s0 = l1_u4(a00, b00) + l1_u4(a01, b01);
        float s1 = l1_u4(a10, b10) + l1_u4(a11, b11);
        float s2 = l1_u4(a20, b20) + l1_u4(a21, b21);
        float s3 = l1_u4(a30, b30) + l1_u4(a31, b31);

        #pragma unroll
        for (int off = 4; off >= 1; off >>= 1) {
            s0 += __shfl_xor(s0, off, 64);
            s1 += __shfl_xor(s1, off, 64);
            s2 += __shfl_xor(s2, off, 64);
            s3 += __shfl_xor(s3, off, 64);
        }

        if (sl == 0) {
            float4 p;
            p.x = expf(expf(-0.01f * s0));
            p.y = expf(expf(-0.01f * s1));
            p.z = expf(expf(-0.01f * s2));
            p.w = expf(expf(-0.01f * s3));
            ((float4*)out)[g] = p;
            atomicAdd(seg_sum + (size_t)d4.x * PAD, p.x);
            atomicAdd(seg_sum + (size_t)d4.y * PAD, p.y);
            atomicAdd(seg_sum + (size_t)d4.z * PAD, p.z);
            atomicAdd(seg_sum + (size_t)d4.w * PAD, p.w);
        }
    } else {
        // tail: per-edge scalar path (not hit for E % 4 == 0)
        for (int e = base; e < E; ++e) {
            int s = src[e], d = dst[e];
            const uint4* fa = (const uint4*)(feats16 + (size_t)s * D_FEAT);
            const uint4* fb = (const uint4*)(feats16 + (size_t)d * D_FEAT);
            uint4 a0 = fa[sl], a1 = fa[sl + 8];
            uint4 b0 = fb[sl], b1 = fb[sl + 8];
            float sum = l1_u4(a0, b0) + l1_u4(a1, b1);
            #pragma unroll
            for (int off = 4; off >= 1; off >>= 1)
                sum += __shfl_xor(sum, off, 64);
            if (sl == 0) {
                float p = expf(expf(-0.01f * sum));
                out[e] = p;
                atomicAdd(seg_sum + (size_t)d * PAD, p);
            }
        }
    }
}

// Dispatch 3: out[e] /= seg_sum[dst[e]*PAD], 4 edges per thread.
__global__ void edge_div_kernel(const int* __restrict__ dst,
                                const float* __restrict__ seg_sum,
                                float* __restrict__ out,
                                int E4) {
    int i = blockIdx.x * blockDim.x + threadIdx.x;
    if (i >= E4) return;
    float4 p = ((const float4*)out)[i];
    int4   d = ((const int4*)dst)[i];
    p.x /= seg_sum[(size_t)d.x * PAD];
    p.y /= seg_sum[(size_t)d.y * PAD];
    p.z /= seg_sum[(size_t)d.z * PAD];
    p.w /= seg_sum[(size_t)d.w * PAD];
    ((float4*)out)[i] = p;
}

__global__ void edge_div_tail_kernel(const int* __restrict__ dst,
                                     const float* __restrict__ seg_sum,
                                     float* __restrict__ out,
                                     int start, int E) {
    int e = start + blockIdx.x * blockDim.x + threadIdx.x;
    if (e >= E) return;
    out[e] = out[e] / seg_sum[(size_t)dst[e] * PAD];
}

extern "C" void kernel_launch(void* const* d_in, const int* in_sizes, int n_in,
                              void* d_out, int out_size, void* d_ws, size_t ws_size,
                              hipStream_t stream) {
    const float* feats = (const float*)d_in[0];
    const int*   eidx  = (const int*)d_in[1];

    const int E = in_sizes[1] / 2;          // 320000
    const int N = in_sizes[0] / D_FEAT;     // 10000

    const int* src = eidx;       // edge_index row 0
    const int* dst = eidx + E;   // edge_index row 1

    float*  seg_sum = (float*)d_ws;                         // [N*PAD]
    __half* feats16 = (__half*)(seg_sum + (size_t)N * PAD); // [N*D]
    float*  out     = (float*)d_out;                        // [E]

    // 1) convert + zero
    {
        int total8 = N * D_FEAT / 8;   // 160000 (> N)
        dim3 blk(256);
        dim3 grd((total8 + 255) / 256);
        convert_zero_kernel<<<grd, blk, 0, stream>>>(feats, feats16,
                                                     seg_sum, total8, N);
    }
    // 2) eval: 8 lanes/group, 4 edges/group -> 128 edges/block
    {
        int ngroups = (E + 3) / 4;
        dim3 blk(256);
        dim3 grd((ngroups * 8 + 255) / 256);
        edge_eval_kernel<<<grd, blk, 0, stream>>>(feats16, src, dst,
                                                  seg_sum, out, E);
    }
    // 3) divide: 4 edges/thread
    {
        int E4 = E >> 2;
        if (E4 > 0) {
            dim3 blk(256);
            dim3 grd((E4 + 255) / 256);
            edge_div_kernel<<<grd, blk, 0, stream>>>(dst, seg_sum, out, E4);
        }
        if (E & 3) {
            int start = E4 << 2;
            edge_div_tail_kernel<<<dim3(1), dim3(64), 0, stream>>>(
                dst, seg_sum, out, start, E);
        }
    }
}

// Round 13
// 34.039 us; speedup vs baseline: 1.0723x; 1.0723x over previous
//
#include <hip/hip_runtime.h>
#include <hip/hip_fp16.h>

#define D_FEAT  128
#define PAD     16      // floats per seg_sum slot = one 64B line per node

// clang ext_vector types: bit-identical to float4/int4 but accepted by
// __builtin_nontemporal_load/store (HIP_vector_type structs are not).
typedef float fv4 __attribute__((ext_vector_type(4)));
typedef int   iv4 __attribute__((ext_vector_type(4)));

// Dispatch 1: convert feats f32 -> f16 and zero the padded seg_sum slots.
// f32 source is read ONCE -> non-temporal load (don't evict table lines).
// feats16 writes stay cached (eval re-reads them).
__global__ void convert_zero_kernel(const float* __restrict__ feats,
                                    __half* __restrict__ feats16,
                                    float* __restrict__ seg_sum,
                                    int total8, int N) {
    int i = blockIdx.x * blockDim.x + threadIdx.x;
    if (i < N) seg_sum[(size_t)i * PAD] = 0.0f;
    if (i >= total8) return;
    fv4 v0 = __builtin_nontemporal_load(((const fv4*)feats) + 2 * i);
    fv4 v1 = __builtin_nontemporal_load(((const fv4*)feats) + 2 * i + 1);
    __half2 h[4];
    h[0] = __floats2half2_rn(v0.x, v0.y);
    h[1] = __floats2half2_rn(v0.z, v0.w);
    h[2] = __floats2half2_rn(v1.x, v1.y);
    h[3] = __floats2half2_rn(v1.z, v1.w);
    ((uint4*)feats16)[i] = *reinterpret_cast<uint4*>(h);
}

__device__ inline float l1_u32(unsigned ua, unsigned ub) {
    __half2 ha = *reinterpret_cast<__half2*>(&ua);
    __half2 hb = *reinterpret_cast<__half2*>(&ub);
    float2 fa = __half22float2(ha);
    float2 fb = __half22float2(hb);
    return fabsf(fa.x - fb.x) + fabsf(fa.y - fb.y);
}
__device__ inline float l1_u4(uint4 a, uint4 b) {
    return l1_u32(a.x, b.x) + l1_u32(a.y, b.y)
         + l1_u32(a.z, b.z) + l1_u32(a.w, b.w);
}

// Dispatch 2: 8 lanes per edge (8 edges per wave64), fp16 rows (2x uint4 per
// lane; 8 lanes x 16B = one 128B line per load). out store is NON-TEMPORAL:
// the 1.28 MB stream must not evict the L2-resident feats16 table.
// seg_sum padded one 64B line/node (R8, -6.4us). seg_max pass dropped:
// softmax shift invariance, e = exp(-0.01*L1) in (0,1] -> exp(e) <= 2.72.
__global__ void edge_eval_kernel(const __half* __restrict__ feats16,
                                 const int* __restrict__ src,
                                 const int* __restrict__ dst,
                                 float* __restrict__ seg_sum,
                                 float* __restrict__ out,
                                 int E) {
    int gtid = blockIdx.x * blockDim.x + threadIdx.x;
    int edge = gtid >> 3;
    int sl   = threadIdx.x & 7;
    if (edge >= E) return;

    int s = src[edge];
    int d = dst[edge];

    const uint4* fa = (const uint4*)(feats16 + (size_t)s * D_FEAT);
    const uint4* fb = (const uint4*)(feats16 + (size_t)d * D_FEAT);
    uint4 a0 = fa[sl];
    uint4 a1 = fa[sl + 8];
    uint4 b0 = fb[sl];
    uint4 b1 = fb[sl + 8];

    float sum = l1_u4(a0, b0) + l1_u4(a1, b1);

    #pragma unroll
    for (int off = 4; off >= 1; off >>= 1)
        sum += __shfl_xor(sum, off, 64);

    if (sl == 0) {
        float p = expf(expf(-0.01f * sum));
        __builtin_nontemporal_store(p, out + edge);
        atomicAdd(seg_sum + (size_t)d * PAD, p);
    }
}

// Dispatch 3: out[e] /= seg_sum[dst[e]*PAD], 4 edges per thread.
// out/dst streams are non-temporal both ways; only seg_sum gathers cache.
__global__ void edge_div_kernel(const int* __restrict__ dst,
                                const float* __restrict__ seg_sum,
                                float* __restrict__ out,
                                int E4) {
    int i = blockIdx.x * blockDim.x + threadIdx.x;
    if (i >= E4) return;
    fv4 p = __builtin_nontemporal_load(((const fv4*)out) + i);
    iv4 d = __builtin_nontemporal_load(((const iv4*)dst) + i);
    p.x /= seg_sum[(size_t)d.x * PAD];
    p.y /= seg_sum[(size_t)d.y * PAD];
    p.z /= seg_sum[(size_t)d.z * PAD];
    p.w /= seg_sum[(size_t)d.w * PAD];
    __builtin_nontemporal_store(p, ((fv4*)out) + i);
}

__global__ void edge_div_tail_kernel(const int* __restrict__ dst,
                                     const float* __restrict__ seg_sum,
                                     float* __restrict__ out,
                                     int start, int E) {
    int e = start + blockIdx.x * blockDim.x + threadIdx.x;
    if (e >= E) return;
    out[e] = out[e] / seg_sum[(size_t)dst[e] * PAD];
}

extern "C" void kernel_launch(void* const* d_in, const int* in_sizes, int n_in,
                              void* d_out, int out_size, void* d_ws, size_t ws_size,
                              hipStream_t stream) {
    const float* feats = (const float*)d_in[0];
    const int*   eidx  = (const int*)d_in[1];

    const int E = in_sizes[1] / 2;          // 320000
    const int N = in_sizes[0] / D_FEAT;     // 10000

    const int* src = eidx;       // edge_index row 0
    const int* dst = eidx + E;   // edge_index row 1

    float*  seg_sum = (float*)d_ws;                         // [N*PAD]
    __half* feats16 = (__half*)(seg_sum + (size_t)N * PAD); // [N*D]
    float*  out     = (float*)d_out;                        // [E]

    // 1) convert + zero
    {
        int total8 = N * D_FEAT / 8;   // 160000 (> N)
        dim3 blk(256);
        dim3 grd((total8 + 255) / 256);
        convert_zero_kernel<<<grd, blk, 0, stream>>>(feats, feats16,
                                                     seg_sum, total8, N);
    }
    // 2) eval: 8 lanes/edge, 32 edges/block
    {
        dim3 blk(256);
        dim3 grd((E + 31) / 32);
        edge_eval_kernel<<<grd, blk, 0, stream>>>(feats16, src, dst,
                                                  seg_sum, out, E);
    }
    // 3) divide: 4 edges/thread
    {
        int E4 = E >> 2;
        if (E4 > 0) {
            dim3 blk(256);
            dim3 grd((E4 + 255) / 256);
            edge_div_kernel<<<grd, blk, 0, stream>>>(dst, seg_sum, out, E4);
        }
        if (E & 3) {
            int start = E4 << 2;
            edge_div_tail_kernel<<<dim3(1), dim3(64), 0, stream>>>(
                dst, seg_sum, out, start, E);
        }
    }
}